// Round 2
// baseline (5636.798 us; speedup 1.0000x reference)
//
#include <hip/hip_runtime.h>
#include <math.h>

#define S_    2048
#define B_    4
#define E_    1024
#define F_    4096
#define H_    16
#define NE_   8
#define CAP_  2048
#define T_    (S_*B_)     // 8192 tokens
#define HD_   (E_/H_)     // 64
#define HALF_ (E_/2)      // 512

typedef unsigned short u16;
typedef unsigned long long u64;

__device__ __forceinline__ float bf2f(u16 u) {
  union { unsigned int i; float f; } v; v.i = ((unsigned int)u) << 16; return v.f;
}
__device__ __forceinline__ u16 f2bf(float f) {
  union { float f; unsigned int i; } v; v.f = f;
  unsigned int x = v.i;
  return (u16)((x + 0x7fffu + ((x >> 16) & 1u)) >> 16);
}

// ---------------- trig tables (fp64 for fidelity to numpy ref) ----------------
__global__ __launch_bounds__(256) void trig_kernel(float* __restrict__ cosT,
                                                   float* __restrict__ sinT) {
  int s = blockIdx.x;
  for (int j = threadIdx.x; j < HALF_; j += 256) {
    double inv = pow(10000.0, -(double)j / (double)HALF_);
    double fr = (double)s * inv;
    cosT[(size_t)s*HALF_ + j] = (float)cos(fr);
    sinT[(size_t)s*HALF_ + j] = (float)sin(fr);
  }
}

// ---------------- LayerNorm (+RoPE) from fp32 input -> fp32 ----------------
__global__ __launch_bounds__(256) void ln_rope_kernel(
    const float* __restrict__ in, const float* __restrict__ sw, const float* __restrict__ bw,
    const float* __restrict__ cosT, const float* __restrict__ sinT,
    float* __restrict__ out) {
  __shared__ float xb[E_];
  __shared__ double red[256];
  __shared__ double stats[2];
  int t = blockIdx.x;
  int s = t / B_;
  const float* row = in + (size_t)t * E_;
  int tid = threadIdx.x;
  double sum = 0.0;
  for (int k = 0; k < 4; k++) {
    int e = tid + k*256;
    float f = row[e];
    xb[e] = f;
    sum += (double)f;
  }
  red[tid] = sum; __syncthreads();
  for (int off = 128; off > 0; off >>= 1) {
    if (tid < off) red[tid] += red[tid+off];
    __syncthreads();
  }
  if (tid == 0) stats[0] = red[0] / (double)E_;
  __syncthreads();
  double m = stats[0];
  double sq = 0.0;
  for (int k = 0; k < 4; k++) {
    int e = tid + k*256;
    double d = (double)xb[e] - m;
    sq += d*d;
  }
  red[tid] = sq; __syncthreads();
  for (int off = 128; off > 0; off >>= 1) {
    if (tid < off) red[tid] += red[tid+off];
    __syncthreads();
  }
  if (tid == 0) stats[1] = 1.0 / sqrt(red[0] / (double)E_ + 1e-5);
  __syncthreads();
  float mf = (float)m, rs = (float)stats[1];
  for (int k = 0; k < 2; k++) {
    int j = tid + k*256;    // 0..511
    float n1 = (xb[j]        - mf)*rs*sw[j]        + bw[j];
    float n2 = (xb[j+HALF_]  - mf)*rs*sw[j+HALF_]  + bw[j+HALF_];
    float c  = cosT[(size_t)s*HALF_ + j];
    float sn = sinT[(size_t)s*HALF_ + j];
    out[(size_t)t*E_ + j]        = n1*c - n2*sn;
    out[(size_t)t*E_ + HALF_+j]  = n1*sn + n2*c;
  }
}

// ---------------- LayerNorm (no rope) from fp32 input -> fp32 ----------------
__global__ __launch_bounds__(256) void ln2_kernel(
    const float* __restrict__ in, const float* __restrict__ sw, const float* __restrict__ bw,
    float* __restrict__ out) {
  __shared__ float xb[E_];
  __shared__ double red[256];
  __shared__ double stats[2];
  int t = blockIdx.x;
  const float* row = in + (size_t)t * E_;
  int tid = threadIdx.x;
  double sum = 0.0;
  for (int k = 0; k < 4; k++) {
    int e = tid + k*256;
    float f = row[e];
    xb[e] = f;
    sum += (double)f;
  }
  red[tid] = sum; __syncthreads();
  for (int off = 128; off > 0; off >>= 1) {
    if (tid < off) red[tid] += red[tid+off];
    __syncthreads();
  }
  if (tid == 0) stats[0] = red[0] / (double)E_;
  __syncthreads();
  double m = stats[0];
  double sq = 0.0;
  for (int k = 0; k < 4; k++) {
    int e = tid + k*256;
    double d = (double)xb[e] - m;
    sq += d*d;
  }
  red[tid] = sq; __syncthreads();
  for (int off = 128; off > 0; off >>= 1) {
    if (tid < off) red[tid] += red[tid+off];
    __syncthreads();
  }
  if (tid == 0) stats[1] = 1.0 / sqrt(red[0] / (double)E_ + 1e-5);
  __syncthreads();
  float mf = (float)m, rs = (float)stats[1];
  for (int k = 0; k < 4; k++) {
    int e = tid + k*256;
    out[(size_t)t*E_ + e] = (xb[e] - mf)*rs*sw[e] + bw[e];
  }
}

// ---------------- generic GEMM: C = A(MxK,f32) * B(NxK,f32)^T + bias (+resid) ----------------
// 128x128 tile, BK=8, 256 threads, 8x8 micro-tile.
__global__ __launch_bounds__(256) void gemm_nt_kernel(
    const float* __restrict__ Abase, const float* __restrict__ Bbase,
    const float* __restrict__ biasbase, const float* __restrict__ resbase,
    float* __restrict__ Cbase,
    int M, int N, int K,
    long long sAz, long long sBz, long long sbiasz, long long sCz, int has_res) {
  const float* A = Abase + (size_t)blockIdx.z * sAz;
  const float* B = Bbase + (size_t)blockIdx.z * sBz;
  const float* bias = biasbase + (size_t)blockIdx.z * sbiasz;
  float* C = Cbase + (size_t)blockIdx.z * sCz;
  __shared__ float As[8][132];
  __shared__ float Bs[8][132];
  int m0 = blockIdx.y * 128, n0 = blockIdx.x * 128;
  int tid = threadIdx.x;
  int w = tid >> 6, l = tid & 63;
  int tx = (w & 1)*8 + (l & 7);      // 0..15
  int ty = (w >> 1)*8 + (l >> 3);    // 0..15
  int arow = tid >> 1, ak = (tid & 1) * 4;
  float acc[8][8] = {};
  for (int k0 = 0; k0 < K; k0 += 8) {
    float4 av = *(const float4*)(A + (size_t)(m0 + arow)*K + k0 + ak);
    As[ak+0][arow] = av.x; As[ak+1][arow] = av.y;
    As[ak+2][arow] = av.z; As[ak+3][arow] = av.w;
    float4 bv = *(const float4*)(B + (size_t)(n0 + arow)*K + k0 + ak);
    Bs[ak+0][arow] = bv.x; Bs[ak+1][arow] = bv.y;
    Bs[ak+2][arow] = bv.z; Bs[ak+3][arow] = bv.w;
    __syncthreads();
#pragma unroll
    for (int kk = 0; kk < 8; kk++) {
      float a[8], b[8];
      *(float4*)&a[0] = *(const float4*)&As[kk][ty*8];
      *(float4*)&a[4] = *(const float4*)&As[kk][ty*8+4];
      *(float4*)&b[0] = *(const float4*)&Bs[kk][tx*8];
      *(float4*)&b[4] = *(const float4*)&Bs[kk][tx*8+4];
#pragma unroll
      for (int i = 0; i < 8; i++)
#pragma unroll
        for (int j = 0; j < 8; j++)
          acc[i][j] = fmaf(a[i], b[j], acc[i][j]);
    }
    __syncthreads();
  }
  for (int i = 0; i < 8; i++) {
    int m = m0 + ty*8 + i;
    float* crow = C + (size_t)m*N + n0 + tx*8;
    const float* rrow = resbase + (size_t)m*N + n0 + tx*8;
#pragma unroll
    for (int j = 0; j < 8; j++) {
      float v = acc[i][j] + bias[n0 + tx*8 + j];
      if (has_res) v += rrow[j];
      crow[j] = v;
    }
  }
}

// ---------------- flash attention, fp32, TQ=32 / TK=64 ----------------
__global__ __launch_bounds__(256) void attn_kernel(
    const float* __restrict__ qp, const float* __restrict__ kp,
    const float* __restrict__ vp, float* __restrict__ ctx) {
  __shared__ float qts[64][36];   // [d][r] (pad 36)
  __shared__ float kts[64][68];   // [d][c] (pad 68)
  __shared__ float vs[64][68];    // [kk][d]
  __shared__ float pts[64][36];   // [c][r]
  __shared__ float mrow[32], lrow[32], arow[32];
  int bh = blockIdx.y;
  int b = bh >> 4, hh = bh & 15;
  int q0 = blockIdx.x * 32;
  int tid = threadIdx.x;
  int w = tid >> 6, l = tid & 63;
  int tx = (w & 1)*8 + (l & 7);      // 0..15
  int ty = (w >> 1)*8 + (l >> 3);    // 0..15
  // load Q tile (32x64), transposed, pre-scaled by 1/sqrt(hd)=0.125
  for (int rep = 0; rep < 2; rep++) {
    int u = tid + rep*256;
    int r = u >> 4, c4 = (u & 15)*4;
    float4 v = *(const float4*)(qp + ((size_t)(q0+r)*B_ + b)*E_ + hh*64 + c4);
    qts[c4+0][r] = v.x*0.125f; qts[c4+1][r] = v.y*0.125f;
    qts[c4+2][r] = v.z*0.125f; qts[c4+3][r] = v.w*0.125f;
  }
  if (tid < 32) { mrow[tid] = -INFINITY; lrow[tid] = 0.f; }
  float acc[2][4] = {};
  for (int kt = 0; kt < S_/64; kt++) {
    __syncthreads();
    for (int rep = 0; rep < 4; rep++) {
      int u = tid + rep*256;
      int r = u >> 4, c4 = (u & 15)*4;
      size_t base = ((size_t)(kt*64 + r)*B_ + b)*E_ + hh*64 + c4;
      float4 kv = *(const float4*)(kp + base);
      kts[c4+0][r] = kv.x; kts[c4+1][r] = kv.y; kts[c4+2][r] = kv.z; kts[c4+3][r] = kv.w;
      float4 vv = *(const float4*)(vp + base);
      *(float4*)&vs[r][c4] = vv;
    }
    __syncthreads();
    // scores: 2 rows x 4 cols per thread
    float sc[2][4] = {};
#pragma unroll 8
    for (int d = 0; d < 64; d++) {
      float2 qv = *(const float2*)&qts[d][ty*2];
      float4 kv = *(const float4*)&kts[d][tx*4];
      sc[0][0] = fmaf(qv.x, kv.x, sc[0][0]);
      sc[0][1] = fmaf(qv.x, kv.y, sc[0][1]);
      sc[0][2] = fmaf(qv.x, kv.z, sc[0][2]);
      sc[0][3] = fmaf(qv.x, kv.w, sc[0][3]);
      sc[1][0] = fmaf(qv.y, kv.x, sc[1][0]);
      sc[1][1] = fmaf(qv.y, kv.y, sc[1][1]);
      sc[1][2] = fmaf(qv.y, kv.z, sc[1][2]);
      sc[1][3] = fmaf(qv.y, kv.w, sc[1][3]);
    }
#pragma unroll
    for (int j = 0; j < 4; j++) {
      pts[tx*4+j][ty*2+0] = sc[0][j];
      pts[tx*4+j][ty*2+1] = sc[1][j];
    }
    __syncthreads();
    if (tid < 32) {
      int r = tid;
      float mold = mrow[r], mx = mold;
      for (int c = 0; c < 64; c++) mx = fmaxf(mx, pts[c][r]);
      float alpha = expf(mold - mx);
      float sum = 0.f;
      for (int c = 0; c < 64; c++) {
        float p = expf(pts[c][r] - mx);
        pts[c][r] = p;
        sum += p;
      }
      lrow[r] = lrow[r]*alpha + sum;
      mrow[r] = mx;
      arow[r] = alpha;
    }
    __syncthreads();
    float a0 = arow[ty*2], a1 = arow[ty*2+1];
#pragma unroll
    for (int j = 0; j < 4; j++) { acc[0][j] *= a0; acc[1][j] *= a1; }
#pragma unroll 8
    for (int kk = 0; kk < 64; kk++) {
      float2 pv = *(const float2*)&pts[kk][ty*2];
      float4 vv = *(const float4*)&vs[kk][tx*4];
      acc[0][0] = fmaf(pv.x, vv.x, acc[0][0]);
      acc[0][1] = fmaf(pv.x, vv.y, acc[0][1]);
      acc[0][2] = fmaf(pv.x, vv.z, acc[0][2]);
      acc[0][3] = fmaf(pv.x, vv.w, acc[0][3]);
      acc[1][0] = fmaf(pv.y, vv.x, acc[1][0]);
      acc[1][1] = fmaf(pv.y, vv.y, acc[1][1]);
      acc[1][2] = fmaf(pv.y, vv.z, acc[1][2]);
      acc[1][3] = fmaf(pv.y, vv.w, acc[1][3]);
    }
  }
  float inv0 = 1.f / lrow[ty*2], inv1 = 1.f / lrow[ty*2+1];
  float4 o0 = make_float4(acc[0][0]*inv0, acc[0][1]*inv0, acc[0][2]*inv0, acc[0][3]*inv0);
  float4 o1 = make_float4(acc[1][0]*inv1, acc[1][1]*inv1, acc[1][2]*inv1, acc[1][3]*inv1);
  *(float4*)(ctx + ((size_t)(q0+ty*2+0)*B_ + b)*E_ + hh*64 + tx*4) = o0;
  *(float4*)(ctx + ((size_t)(q0+ty*2+1)*B_ + b)*E_ + hh*64 + tx*4) = o1;
}

// ---------------- router: logits (fp64 accum) + argmax ----------------
__global__ __launch_bounds__(256) void router_kernel(
    const float* __restrict__ xn, const float* __restrict__ rw, int* __restrict__ top) {
  __shared__ float lg[32][9];
  int t0 = blockIdx.x * 32;
  int tl = threadIdx.x >> 3;
  int n = threadIdx.x & 7;
  int t = t0 + tl;
  const float* xr = xn + (size_t)t * E_;
  double acc = 0.0;
  for (int e = 0; e < E_; e++) acc += (double)xr[e] * (double)rw[e*NE_ + n];
  lg[tl][n] = (float)acc;
  __syncthreads();
  if (n == 0) {
    float best = lg[tl][0]; int bi = 0;
    for (int i = 1; i < 8; i++) {
      float v = lg[tl][i];
      if (v > best) { best = v; bi = i; }
    }
    top[t] = bi;
  }
}

// ---------------- capacity (Switch cumsum) ----------------
__global__ __launch_bounds__(256) void capacity_kernel(
    const int* __restrict__ top, int* __restrict__ elist, int* __restrict__ ecount) {
  __shared__ int tl[T_];            // 32 KB
  __shared__ int cnts[256][NE_];    // 8 KB
  int tid = threadIdx.x;
  for (int i = tid; i < T_; i += 256) tl[i] = top[i];
  __syncthreads();
  int c[NE_] = {};
  int base = tid * 32;
  for (int i = 0; i < 32; i++) c[tl[base+i]]++;
  for (int n = 0; n < NE_; n++) cnts[tid][n] = c[n];
  __syncthreads();
  if (tid < NE_) {
    int run = 0;
    for (int i = 0; i < 256; i++) {
      int v = cnts[i][tid];
      cnts[i][tid] = run;
      run += v;
    }
    ecount[tid] = min(run, CAP_);
  }
  __syncthreads();
  int pos[NE_];
  for (int n = 0; n < NE_; n++) pos[n] = cnts[tid][n];
  for (int i = 0; i < 32; i++) {
    int t = base + i;
    int e = tl[t];
    int p = pos[e]++;
    if (p < CAP_) elist[e*CAP_ + p] = t;
  }
}

// ---------------- out = x for all tokens (dropped tokens keep residual) ----------------
__global__ __launch_bounds__(256) void fill_out_kernel(
    const float* __restrict__ x, float* __restrict__ out) {
  size_t i4 = ((size_t)blockIdx.x*256 + threadIdx.x) * 4;
  *(float4*)(out + i4) = *(const float4*)(x + i4);
}

// ---------------- expert FFN stage 1: h = gelu(xn @ wi[e]), bf16 out ----------------
__global__ __launch_bounds__(256) void expert_ffn1_kernel(
    const float* __restrict__ xn, const float* __restrict__ wi,
    const int* __restrict__ elist, const int* __restrict__ ecount,
    u16* __restrict__ h) {
  int e = blockIdx.z;
  int cnt = ecount[e];
  int t0 = blockIdx.y * 128;
  if (t0 >= cnt) return;
  int n0 = blockIdx.x * 128;
  const float* W = wi + (size_t)e * E_ * F_;
  __shared__ float As[8][132];
  __shared__ float Bs[8][132];
  __shared__ int toks[128];
  int tid = threadIdx.x;
  for (int i = tid; i < 128; i += 256) {
    int r = t0 + i;
    toks[i] = (r < cnt) ? elist[e*CAP_ + r] : -1;
  }
  __syncthreads();
  int w = tid >> 6, l = tid & 63;
  int tx = (w & 1)*8 + (l & 7);
  int ty = (w >> 1)*8 + (l >> 3);
  int arow = tid >> 1, ak = (tid & 1)*4;
  int bk = tid >> 5, bn = (tid & 31)*4;
  int tokA = toks[arow];
  float acc[8][8] = {};
  for (int k0 = 0; k0 < E_; k0 += 8) {
    float4 av = make_float4(0.f,0.f,0.f,0.f);
    if (tokA >= 0) av = *(const float4*)(xn + (size_t)tokA*E_ + k0 + ak);
    As[ak+0][arow] = av.x; As[ak+1][arow] = av.y;
    As[ak+2][arow] = av.z; As[ak+3][arow] = av.w;
    float4 bv = *(const float4*)(W + (size_t)(k0 + bk)*F_ + n0 + bn);
    Bs[bk][bn+0] = bv.x; Bs[bk][bn+1] = bv.y;
    Bs[bk][bn+2] = bv.z; Bs[bk][bn+3] = bv.w;
    __syncthreads();
#pragma unroll
    for (int kk = 0; kk < 8; kk++) {
      float a[8], b[8];
      *(float4*)&a[0] = *(const float4*)&As[kk][ty*8];
      *(float4*)&a[4] = *(const float4*)&As[kk][ty*8+4];
      *(float4*)&b[0] = *(const float4*)&Bs[kk][tx*8];
      *(float4*)&b[4] = *(const float4*)&Bs[kk][tx*8+4];
#pragma unroll
      for (int i = 0; i < 8; i++)
#pragma unroll
        for (int j = 0; j < 8; j++)
          acc[i][j] = fmaf(a[i], b[j], acc[i][j]);
    }
    __syncthreads();
  }
  for (int i = 0; i < 8; i++) {
    int tok = toks[ty*8 + i];
    if (tok < 0) continue;
    u16* hp = h + (size_t)tok*F_ + n0 + tx*8;
#pragma unroll
    for (int j = 0; j < 8; j++) {
      float v = acc[i][j];
      v = 0.5f * v * (1.0f + erff(v * 0.70710678118654752f));
      hp[j] = f2bf(v);
    }
  }
}

// ---------------- expert FFN stage 2: out = x + h @ wo[e] ----------------
__global__ __launch_bounds__(256) void expert_ffn2_kernel(
    const u16* __restrict__ h, const float* __restrict__ wo,
    const int* __restrict__ elist, const int* __restrict__ ecount,
    const float* __restrict__ x, float* __restrict__ out) {
  int e = blockIdx.z;
  int cnt = ecount[e];
  int t0 = blockIdx.y * 128;
  if (t0 >= cnt) return;
  int n0 = blockIdx.x * 128;
  const float* W = wo + (size_t)e * F_ * E_;
  __shared__ float As[8][132];
  __shared__ float Bs[8][132];
  __shared__ int toks[128];
  int tid = threadIdx.x;
  for (int i = tid; i < 128; i += 256) {
    int r = t0 + i;
    toks[i] = (r < cnt) ? elist[e*CAP_ + r] : -1;
  }
  __syncthreads();
  int w = tid >> 6, l = tid & 63;
  int tx = (w & 1)*8 + (l & 7);
  int ty = (w >> 1)*8 + (l >> 3);
  int arow = tid >> 1, ak = (tid & 1)*4;
  int bk = tid >> 5, bn = (tid & 31)*4;
  int tokA = toks[arow];
  float acc[8][8] = {};
  for (int k0 = 0; k0 < F_; k0 += 8) {
    u64 hv = 0;
    if (tokA >= 0) hv = *(const u64*)(h + (size_t)tokA*F_ + k0 + ak);
    As[ak+0][arow] = bf2f((u16)hv);
    As[ak+1][arow] = bf2f((u16)(hv >> 16));
    As[ak+2][arow] = bf2f((u16)(hv >> 32));
    As[ak+3][arow] = bf2f((u16)(hv >> 48));
    float4 bv = *(const float4*)(W + (size_t)(k0 + bk)*E_ + n0 + bn);
    Bs[bk][bn+0] = bv.x; Bs[bk][bn+1] = bv.y;
    Bs[bk][bn+2] = bv.z; Bs[bk][bn+3] = bv.w;
    __syncthreads();
#pragma unroll
    for (int kk = 0; kk < 8; kk++) {
      float a[8], b[8];
      *(float4*)&a[0] = *(const float4*)&As[kk][ty*8];
      *(float4*)&a[4] = *(const float4*)&As[kk][ty*8+4];
      *(float4*)&b[0] = *(const float4*)&Bs[kk][tx*8];
      *(float4*)&b[4] = *(const float4*)&Bs[kk][tx*8+4];
#pragma unroll
      for (int i = 0; i < 8; i++)
#pragma unroll
        for (int j = 0; j < 8; j++)
          acc[i][j] = fmaf(a[i], b[j], acc[i][j]);
    }
    __syncthreads();
  }
  for (int i = 0; i < 8; i++) {
    int tok = toks[ty*8 + i];
    if (tok < 0) continue;
    const float* xr = x + (size_t)tok*E_ + n0 + tx*8;
    float* op = out + (size_t)tok*E_ + n0 + tx*8;
#pragma unroll
    for (int j = 0; j < 8; j++)
      op[j] = acc[i][j] + xr[j];
  }
}

extern "C" void kernel_launch(void* const* d_in, const int* in_sizes, int n_in,
                              void* d_out, int out_size, void* d_ws, size_t ws_size,
                              hipStream_t stream) {
  (void)in_sizes; (void)n_in; (void)out_size; (void)ws_size;
  const float* query      = (const float*)d_in[0];
  const float* key        = (const float*)d_in[1];
  const float* value      = (const float*)d_in[2];
  const float* in_proj_w  = (const float*)d_in[3];
  const float* in_proj_b  = (const float*)d_in[4];
  const float* out_proj_w = (const float*)d_in[5];
  const float* out_proj_b = (const float*)d_in[6];
  const float* norm1_s    = (const float*)d_in[7];
  const float* norm1_b    = (const float*)d_in[8];
  const float* norm2_s    = (const float*)d_in[9];
  const float* norm2_b    = (const float*)d_in[10];
  const float* router_w   = (const float*)d_in[11];
  const float* wi         = (const float*)d_in[12];
  const float* wo         = (const float*)d_in[13];
  float* out = (float*)d_out;

  float* ws = (float*)d_ws;
  const size_t TE = (size_t)T_ * E_;
  float* qn  = ws;
  float* kn  = ws + TE;
  float* vn  = ws + 2*TE;
  float* qp  = ws + 3*TE;
  float* kp  = ws + 4*TE;
  float* vp  = ws + 5*TE;
  float* ctx = qn;              // reuse (qn dead after projections)
  float* x   = kn;              // residual
  float* xn  = vn;              // post-LN2
  float* cosT = ws + 6*TE;
  float* sinT = cosT + (size_t)S_*HALF_;
  u16* hbuf = (u16*)(ws + 3*TE);    // overlays qp/kp (dead after attention), T_*F_ u16 = 2*TE floats
  int* top    = (int*)(sinT + (size_t)S_*HALF_);
  int* elist  = top + T_;
  int* ecount = elist + NE_*CAP_;
  // total ws use: 6*TE + 2*S*HALF floats + ~25k ints ≈ 210 MB

  trig_kernel<<<dim3(S_), dim3(256), 0, stream>>>(cosT, sinT);
  ln_rope_kernel<<<dim3(T_), dim3(256), 0, stream>>>(query, norm1_s, norm1_b, cosT, sinT, qn);
  ln_rope_kernel<<<dim3(T_), dim3(256), 0, stream>>>(key,   norm1_s, norm1_b, cosT, sinT, kn);
  ln_rope_kernel<<<dim3(T_), dim3(256), 0, stream>>>(value, norm1_s, norm1_b, cosT, sinT, vn);
  // QKV projections: z = 0,1,2 -> (qn,kn,vn) x in_proj_w slices -> (qp,kp,vp)
  gemm_nt_kernel<<<dim3(E_/128, T_/128, 3), dim3(256), 0, stream>>>(
      qn, in_proj_w, in_proj_b, qn /*unused*/, qp,
      T_, E_, E_, (long long)TE, (long long)E_*E_, (long long)E_, (long long)TE, 0);
  attn_kernel<<<dim3(S_/32, B_*H_), dim3(256), 0, stream>>>(qp, kp, vp, ctx);
  // out-proj + residual(query)
  gemm_nt_kernel<<<dim3(E_/128, T_/128, 1), dim3(256), 0, stream>>>(
      ctx, out_proj_w, out_proj_b, query, x,
      T_, E_, E_, 0, 0, 0, 0, 1);
  ln2_kernel<<<dim3(T_), dim3(256), 0, stream>>>(x, norm2_s, norm2_b, xn);
  router_kernel<<<dim3(T_/32), dim3(256), 0, stream>>>(xn, router_w, top);
  capacity_kernel<<<dim3(1), dim3(256), 0, stream>>>(top, elist, ecount);
  fill_out_kernel<<<dim3(TE/1024), dim3(256), 0, stream>>>(x, out);
  expert_ffn1_kernel<<<dim3(F_/128, CAP_/128, NE_), dim3(256), 0, stream>>>(
      xn, wi, elist, ecount, hbuf);
  expert_ffn2_kernel<<<dim3(E_/128, CAP_/128, NE_), dim3(256), 0, stream>>>(
      hbuf, wo, elist, ecount, x, out);
}

// Round 3
// 2582.701 us; speedup vs baseline: 2.1825x; 2.1825x over previous
//
#include <hip/hip_runtime.h>
#include <math.h>

#define S_    2048
#define B_    4
#define E_    1024
#define F_    4096
#define H_    16
#define NE_   8
#define CAP_  2048
#define T_    (S_*B_)     // 8192 tokens
#define HALF_ (E_/2)      // 512

typedef unsigned short u16;
typedef unsigned long long u64;
typedef __attribute__((ext_vector_type(8))) short bf16x8;
typedef __attribute__((ext_vector_type(4))) float f32x4;

__device__ __forceinline__ float bf2f(u16 u) {
  union { unsigned int i; float f; } v; v.i = ((unsigned int)u) << 16; return v.f;
}
__device__ __forceinline__ u16 f2bf(float f) {
  union { float f; unsigned int i; } v; v.f = f;
  unsigned int x = v.i;
  return (u16)((x + 0x7fffu + ((x >> 16) & 1u)) >> 16);
}
__device__ __forceinline__ void splitf(float v, u16& hi, u16& lo) {
  hi = f2bf(v);
  lo = f2bf(v - bf2f(hi));
}
__device__ __forceinline__ f32x4 mfma16(bf16x8 a, bf16x8 b, f32x4 c) {
  return __builtin_amdgcn_mfma_f32_16x16x32_bf16(a, b, c, 0, 0, 0);
}

// ---------------- trig tables (fp64) ----------------
__global__ __launch_bounds__(256) void trig_kernel(float* __restrict__ cosT,
                                                   float* __restrict__ sinT) {
  int s = blockIdx.x;
  for (int j = threadIdx.x; j < HALF_; j += 256) {
    double inv = pow(10000.0, -(double)j / (double)HALF_);
    double fr = (double)s * inv;
    cosT[(size_t)s*HALF_ + j] = (float)cos(fr);
    sinT[(size_t)s*HALF_ + j] = (float)sin(fr);
  }
}

// ---------------- split fp32 -> bf16 hi/lo ----------------
__global__ __launch_bounds__(256) void split_kernel(const float* __restrict__ src,
                                                    u16* __restrict__ hi, u16* __restrict__ lo, int n) {
  int i = blockIdx.x*256 + threadIdx.x;
  if (i < n) {
    float v = src[i];
    u16 h, l; splitf(v, h, l);
    hi[i] = h; lo[i] = l;
  }
}

// ---------------- transpose + convert: src fp32 [Z][R][C] -> dst bf16 [Z][C][R] ----------------
__global__ __launch_bounds__(256) void transp_bf16_kernel(const float* __restrict__ src,
                                                          u16* __restrict__ dst, int R, int C) {
  int z = blockIdx.z;
  src += (size_t)z*R*C; dst += (size_t)z*R*C;
  __shared__ float tile[32][33];
  int r0 = blockIdx.y*32, c0 = blockIdx.x*32;
  int tr = threadIdx.x >> 5, tc = threadIdx.x & 31;
  for (int i = 0; i < 4; i++)
    tile[tr + i*8][tc] = src[(size_t)(r0 + tr + i*8)*C + c0 + tc];
  __syncthreads();
  for (int i = 0; i < 4; i++)
    dst[(size_t)(c0 + tr + i*8)*R + r0 + tc] = f2bf(tile[tc][tr + i*8]);
}

// ---------------- LayerNorm + RoPE -> bf16 hi/lo ----------------
__global__ __launch_bounds__(256) void ln_rope_kernel(
    const float* __restrict__ in, const float* __restrict__ sw, const float* __restrict__ bw,
    const float* __restrict__ cosT, const float* __restrict__ sinT,
    u16* __restrict__ outh, u16* __restrict__ outl) {
  __shared__ float xb[E_];
  __shared__ double red[256];
  __shared__ double stats[2];
  int t = blockIdx.x;
  int s = t / B_;
  const float* row = in + (size_t)t * E_;
  int tid = threadIdx.x;
  double sum = 0.0;
  for (int k = 0; k < 4; k++) {
    int e = tid + k*256;
    float f = row[e];
    xb[e] = f;
    sum += (double)f;
  }
  red[tid] = sum; __syncthreads();
  for (int off = 128; off > 0; off >>= 1) {
    if (tid < off) red[tid] += red[tid+off];
    __syncthreads();
  }
  if (tid == 0) stats[0] = red[0] / (double)E_;
  __syncthreads();
  double m = stats[0];
  double sq = 0.0;
  for (int k = 0; k < 4; k++) {
    int e = tid + k*256;
    double d = (double)xb[e] - m;
    sq += d*d;
  }
  red[tid] = sq; __syncthreads();
  for (int off = 128; off > 0; off >>= 1) {
    if (tid < off) red[tid] += red[tid+off];
    __syncthreads();
  }
  if (tid == 0) stats[1] = 1.0 / sqrt(red[0] / (double)E_ + 1e-5);
  __syncthreads();
  float mf = (float)m, rs = (float)stats[1];
  for (int k = 0; k < 2; k++) {
    int j = tid + k*256;    // 0..511
    float n1 = (xb[j]        - mf)*rs*sw[j]        + bw[j];
    float n2 = (xb[j+HALF_]  - mf)*rs*sw[j+HALF_]  + bw[j+HALF_];
    float c  = cosT[(size_t)s*HALF_ + j];
    float sn = sinT[(size_t)s*HALF_ + j];
    float o1 = n1*c - n2*sn;
    float o2 = n1*sn + n2*c;
    u16 h, l;
    splitf(o1, h, l);
    outh[(size_t)t*E_ + j] = h; outl[(size_t)t*E_ + j] = l;
    splitf(o2, h, l);
    outh[(size_t)t*E_ + HALF_ + j] = h; outl[(size_t)t*E_ + HALF_ + j] = l;
  }
}

// ---------------- LayerNorm (no rope) -> fp32 xn + bf16 xnb ----------------
__global__ __launch_bounds__(256) void ln2_kernel(
    const float* __restrict__ in, const float* __restrict__ sw, const float* __restrict__ bw,
    float* __restrict__ out, u16* __restrict__ outb) {
  __shared__ float xb[E_];
  __shared__ double red[256];
  __shared__ double stats[2];
  int t = blockIdx.x;
  const float* row = in + (size_t)t * E_;
  int tid = threadIdx.x;
  double sum = 0.0;
  for (int k = 0; k < 4; k++) {
    int e = tid + k*256;
    float f = row[e];
    xb[e] = f;
    sum += (double)f;
  }
  red[tid] = sum; __syncthreads();
  for (int off = 128; off > 0; off >>= 1) {
    if (tid < off) red[tid] += red[tid+off];
    __syncthreads();
  }
  if (tid == 0) stats[0] = red[0] / (double)E_;
  __syncthreads();
  double m = stats[0];
  double sq = 0.0;
  for (int k = 0; k < 4; k++) {
    int e = tid + k*256;
    double d = (double)xb[e] - m;
    sq += d*d;
  }
  red[tid] = sq; __syncthreads();
  for (int off = 128; off > 0; off >>= 1) {
    if (tid < off) red[tid] += red[tid+off];
    __syncthreads();
  }
  if (tid == 0) stats[1] = 1.0 / sqrt(red[0] / (double)E_ + 1e-5);
  __syncthreads();
  float mf = (float)m, rs = (float)stats[1];
  for (int k = 0; k < 4; k++) {
    int e = tid + k*256;
    float v = (xb[e] - mf)*rs*sw[e] + bw[e];
    out[(size_t)t*E_ + e] = v;
    outb[(size_t)t*E_ + e] = f2bf(v);
  }
}

// ---------------- MFMA GEMM: C = A[M][K] * B[N][K]^T ----------------
// MODE 0: split-3x, +bias, store bf16 hi/lo (QKV, z=0..2 selects slice)
// MODE 1: split-3x, +bias +res, store fp32 (out-proj)
// MODE 2: plain, gather rows, gelu -> bf16 (ffn1, z=expert)
// MODE 3: plain, gather rows, +res -> fp32 (ffn2, z=expert)
template<int MODE>
__global__ __launch_bounds__(256) void gemm_mfma(
    const u16* __restrict__ Ah, const u16* __restrict__ Al,
    const u16* __restrict__ Bh, const u16* __restrict__ Bl,
    const float* __restrict__ bias, const float* __restrict__ res,
    float* __restrict__ Cf, u16* __restrict__ Ch, u16* __restrict__ Cl,
    int M, int N, int K,
    const int* __restrict__ elist, const int* __restrict__ ecount) {
  constexpr bool SPLIT  = (MODE <= 1);
  constexpr bool GATHER = (MODE >= 2);
  __shared__ u16 Ash[128][40];
  __shared__ u16 Bsh[128][40];
  __shared__ u16 Asl[SPLIT?128:1][SPLIT?40:1];
  __shared__ u16 Bsl[SPLIT?128:1][SPLIT?40:1];
  __shared__ int toks[GATHER?128:1];
  int tid = threadIdx.x;
  int m0 = blockIdx.y*128, n0 = blockIdx.x*128;
  if constexpr (MODE == 0) {
    int z = blockIdx.z;
    Ah += (size_t)z*M*K;  Al += (size_t)z*M*K;
    Bh += (size_t)z*N*K;  Bl += (size_t)z*N*K;
    bias += (size_t)z*N;
    Ch += (size_t)z*M*N;  Cl += (size_t)z*M*N;
  }
  if constexpr (GATHER) {
    int e = blockIdx.z;
    int cnt = ecount[e];
    if (m0 >= cnt) return;
    Bh += (size_t)e*N*K;
    const int* el = elist + e*CAP_;
    for (int i = tid; i < 128; i += 256) {
      int r = m0 + i;
      toks[i] = (r < cnt) ? el[r] : -1;
    }
    __syncthreads();
  }
  int wave = tid>>6, lane = tid&63, quad = lane>>4, l16 = lane&15;
  int wm = (wave>>1)*64, wn = (wave&1)*64;
  f32x4 acc[4][4];
  for (int i = 0; i < 4; i++)
    for (int j = 0; j < 4; j++)
      acc[i][j] = f32x4{0.f, 0.f, 0.f, 0.f};
  for (int k0 = 0; k0 < K; k0 += 32) {
    for (int c = tid; c < 512; c += 256) {
      int r = c >> 2, k8 = (c & 3) * 8;
      if constexpr (GATHER) {
        int tok = toks[r];
        int4 va = {0,0,0,0};
        if (tok >= 0) va = *(const int4*)(Ah + (size_t)tok*K + k0 + k8);
        *(int4*)&Ash[r][k8] = va;
      } else {
        *(int4*)&Ash[r][k8] = *(const int4*)(Ah + (size_t)(m0+r)*K + k0 + k8);
        if constexpr (SPLIT)
          *(int4*)&Asl[r][k8] = *(const int4*)(Al + (size_t)(m0+r)*K + k0 + k8);
      }
      *(int4*)&Bsh[r][k8] = *(const int4*)(Bh + (size_t)(n0+r)*K + k0 + k8);
      if constexpr (SPLIT)
        *(int4*)&Bsl[r][k8] = *(const int4*)(Bl + (size_t)(n0+r)*K + k0 + k8);
    }
    __syncthreads();
    bf16x8 af[4], bf[4];
#pragma unroll
    for (int t4 = 0; t4 < 4; t4++) {
      af[t4] = *(const bf16x8*)&Ash[wm + t4*16 + l16][quad*8];
      bf[t4] = *(const bf16x8*)&Bsh[wn + t4*16 + l16][quad*8];
    }
    if constexpr (SPLIT) {
      bf16x8 afl[4], bfl[4];
#pragma unroll
      for (int t4 = 0; t4 < 4; t4++) {
        afl[t4] = *(const bf16x8*)&Asl[wm + t4*16 + l16][quad*8];
        bfl[t4] = *(const bf16x8*)&Bsl[wn + t4*16 + l16][quad*8];
      }
#pragma unroll
      for (int i = 0; i < 4; i++)
#pragma unroll
        for (int j = 0; j < 4; j++) {
          f32x4 a = acc[i][j];
          a = mfma16(af[i],  bf[j],  a);
          a = mfma16(af[i],  bfl[j], a);
          a = mfma16(afl[i], bf[j],  a);
          acc[i][j] = a;
        }
    } else {
#pragma unroll
      for (int i = 0; i < 4; i++)
#pragma unroll
        for (int j = 0; j < 4; j++)
          acc[i][j] = mfma16(af[i], bf[j], acc[i][j]);
    }
    __syncthreads();
  }
  for (int i = 0; i < 4; i++) {
    for (int j = 0; j < 4; j++) {
      for (int r = 0; r < 4; r++) {
        int rl  = wm + i*16 + quad*4 + r;
        int col = n0 + wn + j*16 + l16;
        float v = acc[i][j][r];
        if constexpr (MODE == 0) {
          v += bias[col];
          u16 hi, lo; splitf(v, hi, lo);
          size_t o = (size_t)(m0+rl)*N + col;
          Ch[o] = hi; Cl[o] = lo;
        } else if constexpr (MODE == 1) {
          size_t o = (size_t)(m0+rl)*N + col;
          Cf[o] = v + bias[col] + res[o];
        } else if constexpr (MODE == 2) {
          int tok = toks[rl];
          if (tok >= 0) {
            float g = 0.5f*v*(1.0f + erff(v*0.70710678118654752f));
            Ch[(size_t)tok*N + col] = f2bf(g);
          }
        } else {
          int tok = toks[rl];
          if (tok >= 0) {
            size_t o = (size_t)tok*N + col;
            Cf[o] = v + res[o];
          }
        }
      }
    }
  }
}

// ---------------- flash attention, split-bf16 MFMA, TQ=64 / TK=64 ----------------
__global__ __launch_bounds__(256) void attn_mfma_kernel(
    const u16* __restrict__ qh_, const u16* __restrict__ ql_,
    const u16* __restrict__ kh_, const u16* __restrict__ kl_,
    const u16* __restrict__ vh_, const u16* __restrict__ vl_,
    u16* __restrict__ ch_, u16* __restrict__ cl_) {
  __shared__ u16 Kh[64][72], Kl[64][72];
  __shared__ u16 Vth[64][72], Vtl[64][72];   // transposed: [d][k]
  __shared__ u16 Ph[64][72], Pl[64][72];     // [q][k]
  int bh = blockIdx.y;
  int b = bh >> 4, hh = bh & 15;
  int q0 = blockIdx.x * 64;
  int tid = threadIdx.x, wave = tid>>6, lane = tid&63, quad = lane>>4, l16 = lane&15;
  // Q fragments direct from global (A-frag: m=l16 row, k=quad*8+j; unscaled, scale after MFMA)
  bf16x8 qfh[2], qfl[2];
  {
    int qrow = q0 + wave*16 + l16;
    size_t base = ((size_t)qrow*B_ + b)*E_ + hh*64;
    for (int st = 0; st < 2; st++) {
      qfh[st] = *(const bf16x8*)(qh_ + base + st*32 + quad*8);
      qfl[st] = *(const bf16x8*)(ql_ + base + st*32 + quad*8);
    }
  }
  float m_i[4], l_i[4];
  f32x4 acc[4];
  for (int r = 0; r < 4; r++) { m_i[r] = -INFINITY; l_i[r] = 0.f; }
  for (int d = 0; d < 4; d++) acc[d] = f32x4{0.f,0.f,0.f,0.f};
  for (int kt = 0; kt < S_/64; kt++) {
    __syncthreads();
    // stage K (hi/lo) and V transposed (hi/lo)
    for (int c = tid; c < 512; c += 256) {
      int r = c >> 3, k8 = (c & 7) * 8;
      size_t gb = ((size_t)(kt*64 + r)*B_ + b)*E_ + hh*64 + k8;
      *(int4*)&Kh[r][k8] = *(const int4*)(kh_ + gb);
      *(int4*)&Kl[r][k8] = *(const int4*)(kl_ + gb);
      u16 tmp[8];
      *(int4*)tmp = *(const int4*)(vh_ + gb);
#pragma unroll
      for (int i = 0; i < 8; i++) Vth[k8+i][r] = tmp[i];
      *(int4*)tmp = *(const int4*)(vl_ + gb);
#pragma unroll
      for (int i = 0; i < 8; i++) Vtl[k8+i][r] = tmp[i];
    }
    __syncthreads();
    // scores: wave's 16q x 64k band, 4 col-tiles
    f32x4 sc[4];
#pragma unroll
    for (int ct = 0; ct < 4; ct++) {
      f32x4 s = f32x4{0.f,0.f,0.f,0.f};
#pragma unroll
      for (int st = 0; st < 2; st++) {
        bf16x8 kh = *(const bf16x8*)&Kh[ct*16 + l16][st*32 + quad*8];
        bf16x8 kl = *(const bf16x8*)&Kl[ct*16 + l16][st*32 + quad*8];
        s = mfma16(qfh[st], kh, s);
        s = mfma16(qfh[st], kl, s);
        s = mfma16(qfl[st], kh, s);
      }
      sc[ct] = s;
    }
#pragma unroll
    for (int ct = 0; ct < 4; ct++)
#pragma unroll
      for (int r = 0; r < 4; r++)
        sc[ct][r] *= 0.125f;
    // online softmax (rows = quad*4+r, cols across 16 lanes x 4 tiles)
    float mx[4], alpha[4], rs[4];
#pragma unroll
    for (int r = 0; r < 4; r++)
      mx[r] = fmaxf(fmaxf(sc[0][r], sc[1][r]), fmaxf(sc[2][r], sc[3][r]));
#pragma unroll
    for (int off = 1; off < 16; off <<= 1)
#pragma unroll
      for (int r = 0; r < 4; r++)
        mx[r] = fmaxf(mx[r], __shfl_xor(mx[r], off, 64));
#pragma unroll
    for (int r = 0; r < 4; r++) {
      float mn = fmaxf(m_i[r], mx[r]);
      alpha[r] = expf(m_i[r] - mn);
      m_i[r] = mn;
      rs[r] = 0.f;
    }
#pragma unroll
    for (int ct = 0; ct < 4; ct++)
#pragma unroll
      for (int r = 0; r < 4; r++) {
        float p = expf(sc[ct][r] - m_i[r]);
        sc[ct][r] = p;
        rs[r] += p;
      }
#pragma unroll
    for (int off = 1; off < 16; off <<= 1)
#pragma unroll
      for (int r = 0; r < 4; r++)
        rs[r] += __shfl_xor(rs[r], off, 64);
#pragma unroll
    for (int r = 0; r < 4; r++)
      l_i[r] = l_i[r]*alpha[r] + rs[r];
    // write P (hi/lo) to LDS: row q = wave*16+quad*4+r, col k = ct*16+l16
#pragma unroll
    for (int ct = 0; ct < 4; ct++)
#pragma unroll
      for (int r = 0; r < 4; r++) {
        u16 hi, lo; splitf(sc[ct][r], hi, lo);
        int q = wave*16 + quad*4 + r;
        int k = ct*16 + l16;
        Ph[q][k] = hi; Pl[q][k] = lo;
      }
    // rescale accumulator
#pragma unroll
    for (int d = 0; d < 4; d++)
#pragma unroll
      for (int r = 0; r < 4; r++)
        acc[d][r] *= alpha[r];
    __syncthreads();
    // PV: A = P (m=q=l16, k), B = V^T (n=d=l16, k)
#pragma unroll
    for (int dt = 0; dt < 4; dt++) {
      f32x4 a = acc[dt];
#pragma unroll
      for (int st = 0; st < 2; st++) {
        bf16x8 ph = *(const bf16x8*)&Ph[wave*16 + l16][st*32 + quad*8];
        bf16x8 pl = *(const bf16x8*)&Pl[wave*16 + l16][st*32 + quad*8];
        bf16x8 vh = *(const bf16x8*)&Vth[dt*16 + l16][st*32 + quad*8];
        bf16x8 vl = *(const bf16x8*)&Vtl[dt*16 + l16][st*32 + quad*8];
        a = mfma16(ph, vh, a);
        a = mfma16(ph, vl, a);
        a = mfma16(pl, vh, a);
      }
      acc[dt] = a;
    }
  }
  // epilogue: ctx = acc / l, store hi/lo
  for (int dt = 0; dt < 4; dt++) {
    for (int r = 0; r < 4; r++) {
      float v = acc[dt][r] / l_i[r];
      int q = q0 + wave*16 + quad*4 + r;
      size_t o = ((size_t)q*B_ + b)*E_ + hh*64 + dt*16 + l16;
      u16 hi, lo; splitf(v, hi, lo);
      ch_[o] = hi; cl_[o] = lo;
    }
  }
}

// ---------------- router: logits (fp64 accum) + argmax ----------------
__global__ __launch_bounds__(256) void router_kernel(
    const float* __restrict__ xn, const float* __restrict__ rw, int* __restrict__ top) {
  __shared__ float lg[32][9];
  int t0 = blockIdx.x * 32;
  int tl = threadIdx.x >> 3;
  int n = threadIdx.x & 7;
  int t = t0 + tl;
  const float* xr = xn + (size_t)t * E_;
  double acc = 0.0;
  for (int e = 0; e < E_; e++) acc += (double)xr[e] * (double)rw[e*NE_ + n];
  lg[tl][n] = (float)acc;
  __syncthreads();
  if (n == 0) {
    float best = lg[tl][0]; int bi = 0;
    for (int i = 1; i < 8; i++) {
      float v = lg[tl][i];
      if (v > best) { best = v; bi = i; }
    }
    top[t] = bi;
  }
}

// ---------------- capacity (Switch cumsum) ----------------
__global__ __launch_bounds__(256) void capacity_kernel(
    const int* __restrict__ top, int* __restrict__ elist, int* __restrict__ ecount) {
  __shared__ int tl[T_];
  __shared__ int cnts[256][NE_];
  int tid = threadIdx.x;
  for (int i = tid; i < T_; i += 256) tl[i] = top[i];
  __syncthreads();
  int c[NE_] = {};
  int base = tid * 32;
  for (int i = 0; i < 32; i++) c[tl[base+i]]++;
  for (int n = 0; n < NE_; n++) cnts[tid][n] = c[n];
  __syncthreads();
  if (tid < NE_) {
    int run = 0;
    for (int i = 0; i < 256; i++) {
      int v = cnts[i][tid];
      cnts[i][tid] = run;
      run += v;
    }
    ecount[tid] = min(run, CAP_);
  }
  __syncthreads();
  int pos[NE_];
  for (int n = 0; n < NE_; n++) pos[n] = cnts[tid][n];
  for (int i = 0; i < 32; i++) {
    int t = base + i;
    int e = tl[t];
    int p = pos[e]++;
    if (p < CAP_) elist[e*CAP_ + p] = t;
  }
}

// ---------------- out = x (dropped tokens keep residual) ----------------
__global__ __launch_bounds__(256) void fill_out_kernel(
    const float* __restrict__ x, float* __restrict__ out) {
  size_t i4 = ((size_t)blockIdx.x*256 + threadIdx.x) * 4;
  *(float4*)(out + i4) = *(const float4*)(x + i4);
}

extern "C" void kernel_launch(void* const* d_in, const int* in_sizes, int n_in,
                              void* d_out, int out_size, void* d_ws, size_t ws_size,
                              hipStream_t stream) {
  (void)in_sizes; (void)n_in; (void)out_size; (void)ws_size;
  const float* query      = (const float*)d_in[0];
  const float* key        = (const float*)d_in[1];
  const float* value      = (const float*)d_in[2];
  const float* in_proj_w  = (const float*)d_in[3];
  const float* in_proj_b  = (const float*)d_in[4];
  const float* out_proj_w = (const float*)d_in[5];
  const float* out_proj_b = (const float*)d_in[6];
  const float* norm1_s    = (const float*)d_in[7];
  const float* norm1_b    = (const float*)d_in[8];
  const float* norm2_s    = (const float*)d_in[9];
  const float* norm2_b    = (const float*)d_in[10];
  const float* router_w   = (const float*)d_in[11];
  const float* wi         = (const float*)d_in[12];
  const float* wo         = (const float*)d_in[13];
  float* out = (float*)d_out;

  char* wsb = (char*)d_ws;
  const size_t TE = (size_t)T_ * E_;          // 8,388,608
  // R1 @0 (134,217,728 B): LN outputs hi/lo [3][T][E]; later wit+wot
  u16* nh  = (u16*)(wsb + 0);                 // 3*TE shorts
  u16* nl  = nh + 3*TE;
  u16* wit = (u16*)(wsb + 0);                 // [8][F][E] bf16
  u16* wot = wit + (size_t)8*F_*E_;
  // R2 @134,217,728 (100,663,296 B): QKV proj hi/lo [3][T][E]; later h + xnb
  u16* pph  = (u16*)(wsb + 134217728ULL);
  u16* ppl  = pph + 3*TE;
  u16* hbuf = (u16*)(wsb + 134217728ULL);     // [T][F] bf16
  u16* xnb  = hbuf + (size_t)T_*F_;
  // R3 @234,881,024 (33,554,432 B): ctx hi/lo; later xn fp32
  u16* ctxh = (u16*)(wsb + 234881024ULL);
  u16* ctxl = ctxh + TE;
  float* xn = (float*)(wsb + 234881024ULL);
  // R4: x fp32
  float* x  = (float*)(wsb + 268435456ULL);
  // R5: trig
  float* cosT = (float*)(wsb + 301989888ULL);
  float* sinT = cosT + (size_t)S_*HALF_;
  // R6: proj weight splits
  u16* iph = (u16*)(wsb + 310378496ULL);
  u16* ipl = iph + (size_t)3*E_*E_;
  u16* oph = ipl + (size_t)3*E_*E_;
  u16* opl = oph + (size_t)E_*E_;
  // R7: routing
  int* top    = (int*)(wsb + 327155712ULL);
  int* elist  = top + T_;
  int* ecount = elist + NE_*CAP_;

  trig_kernel<<<dim3(S_), dim3(256), 0, stream>>>(cosT, sinT);
  split_kernel<<<dim3((3*E_*E_)/256), dim3(256), 0, stream>>>(in_proj_w, iph, ipl, 3*E_*E_);
  split_kernel<<<dim3((E_*E_)/256), dim3(256), 0, stream>>>(out_proj_w, oph, opl, E_*E_);
  ln_rope_kernel<<<dim3(T_), dim3(256), 0, stream>>>(query, norm1_s, norm1_b, cosT, sinT, nh,        nl);
  ln_rope_kernel<<<dim3(T_), dim3(256), 0, stream>>>(key,   norm1_s, norm1_b, cosT, sinT, nh + TE,   nl + TE);
  ln_rope_kernel<<<dim3(T_), dim3(256), 0, stream>>>(value, norm1_s, norm1_b, cosT, sinT, nh + 2*TE, nl + 2*TE);
  // QKV projections (split-3x): z selects (qn,kn,vn) x in_proj slice -> pph/ppl
  gemm_mfma<0><<<dim3(E_/128, T_/128, 3), dim3(256), 0, stream>>>(
      nh, nl, iph, ipl, in_proj_b, nullptr, nullptr, pph, ppl,
      T_, E_, E_, nullptr, nullptr);
  // wi/wo transpose+convert (R1 now free)
  transp_bf16_kernel<<<dim3(F_/32, E_/32, 8), dim3(256), 0, stream>>>(wi, wit, E_, F_);
  transp_bf16_kernel<<<dim3(E_/32, F_/32, 8), dim3(256), 0, stream>>>(wo, wot, F_, E_);
  attn_mfma_kernel<<<dim3(S_/64, B_*H_), dim3(256), 0, stream>>>(
      pph, ppl, pph + TE, ppl + TE, pph + 2*TE, ppl + 2*TE, ctxh, ctxl);
  // out-proj (split-3x) + bias + residual(query) -> x fp32
  gemm_mfma<1><<<dim3(E_/128, T_/128, 1), dim3(256), 0, stream>>>(
      ctxh, ctxl, oph, opl, out_proj_b, query, x, nullptr, nullptr,
      T_, E_, E_, nullptr, nullptr);
  ln2_kernel<<<dim3(T_), dim3(256), 0, stream>>>(x, norm2_s, norm2_b, xn, xnb);
  router_kernel<<<dim3(T_/32), dim3(256), 0, stream>>>(xn, router_w, top);
  capacity_kernel<<<dim3(1), dim3(256), 0, stream>>>(top, elist, ecount);
  fill_out_kernel<<<dim3(TE/1024), dim3(256), 0, stream>>>(x, out);
  // expert FFN (plain bf16 MFMA, gathered)
  gemm_mfma<2><<<dim3(F_/128, CAP_/128, NE_), dim3(256), 0, stream>>>(
      xnb, nullptr, wit, nullptr, nullptr, nullptr, nullptr, hbuf, nullptr,
      T_, F_, E_, elist, ecount);
  gemm_mfma<3><<<dim3(E_/128, CAP_/128, NE_), dim3(256), 0, stream>>>(
      hbuf, nullptr, wot, nullptr, nullptr, x, out, nullptr, nullptr,
      T_, E_, F_, elist, ecount);
}